// Round 11
// baseline (915.480 us; speedup 1.0000x reference)
//
#include <hip/hip_runtime.h>
#include <hip/hip_bf16.h>
#include <hip/hip_cooperative_groups.h>

namespace cg = cooperative_groups;

#define N_NODES 100000
#define N_EDGES 1600000
#define NC 40
#define CAP 64               // bucket capacity; data max-degree ~45 << 64

#define XRANGE 12500         // N_NODES / 8 : destination slice per XCD
#define FILL_CHUNK  2048     // edges per virtual block (256 thr x 8)
#define FILL_CHUNKS 782      // ceil(N_EDGES/FILL_CHUNK)
#define FILL_BLOCKS (8 * FILL_CHUNKS)      // 6256 (R5-proven 8-window config)
#define MF_BLOCKS 1563       // ceil(100000/64): 64 rows/vb = 4 waves x 16 rows
#define FB_BLOCKS 6250       // fused agg virtual blocks: 16 nodes each
#define PREP_BLOCKS 250      // 64 Wt0 + 64 Wt1 + 24 Wtc + 98 cnt-zero
#define COOP_GRID 1024       // 4 blocks/CU x 256 CU co-resident

typedef _Float16 half8 __attribute__((ext_vector_type(8)));
typedef float f32x4 __attribute__((ext_vector_type(4)));

// ---- bf16 helpers (packed 2x16 in a uint) ----
__device__ __forceinline__ float bflo(unsigned u) { return __uint_as_float(u << 16); }
__device__ __forceinline__ float bfhi(unsigned u) { return __uint_as_float(u & 0xffff0000u); }
__device__ __forceinline__ unsigned f2bf(float f) {
    unsigned u = __float_as_uint(f);
    return (u + 0x7fffu + ((u >> 16) & 1u)) >> 16;
}

// ================= phase bodies (all R8-proven, blockIdx -> vb) =================

// ---- P0: W transpose fp32->fp16 + cnt zeroing. 250 virtual blocks.
// vb [0,64): Wt0 (16384 = 64x256), [64,128): Wt1, [128,152): Wtc (6144 = 24x256),
// [152,250): cnt zero (25000 int4 exactly, 98x256 = 25088 slots, guarded).
__device__ __forceinline__ void prep_body(int vb, int tx,
                                          const float* __restrict__ w0,
                                          const float* __restrict__ w1,
                                          const float* __restrict__ wc,
                                          _Float16* __restrict__ Wt0,
                                          _Float16* __restrict__ Wt1,
                                          _Float16* __restrict__ Wtc,
                                          int* __restrict__ cnt) {
    if (vb < 128) {
        const float* W = (vb >= 64) ? w1 : w0;
        _Float16* T = (vb >= 64) ? Wt1 : Wt0;
        int e = (vb & 63) * 256 + tx;      // < 16384
        int n = e >> 7, k = e & 127;       // n < 128
        T[e] = (_Float16)W[k * 128 + n];
    } else if (vb < 152) {
        int e = (vb - 128) * 256 + tx;     // < 6144 -> n < 48
        int n = e >> 7, k = e & 127;
        Wtc[e] = (_Float16)((n < NC) ? wc[k * NC + n] : 0.f);
    } else {
        int t4 = (vb - 152) * 256 + tx;
        if (t4 < 25000) ((int4*)cnt)[t4] = make_int4(0, 0, 0, 0);
    }
}

// ---- MFMA fp16 GEMM body: hb = bf16((A @ W) [* dis]). Per wave: 16 rows x 128.
// A-frag: lane holds A[rowBase+(l&15)][8*(l>>4)+i]; W-frag same slot->k bijection
// -> layout-map invariant; C/D layout per learn_hip m89.
// hb: uint at [r*64+c] = features (c, c+64) of row r. dis==nullptr -> unscaled.
__device__ __forceinline__ void gemm_mfma_body(int rowBase, const float* __restrict__ A,
                                               int lda, const _Float16* __restrict__ Wt,
                                               const float* __restrict__ dis,
                                               unsigned* __restrict__ hbU) {
    if (rowBase >= N_NODES) return;
    int lane = threadIdx.x & 63;
    int q = lane & 15, g = lane >> 4;

    const float* ap = A + (size_t)(rowBase + q) * lda + 8 * g;
    half8 a[4];
#pragma unroll
    for (int s = 0; s < 4; s++) {
        float4 lo = *(const float4*)(ap + 32 * s);
        float4 hi = *(const float4*)(ap + 32 * s + 4);
        half8 h;
        h[0] = (_Float16)lo.x; h[1] = (_Float16)lo.y;
        h[2] = (_Float16)lo.z; h[3] = (_Float16)lo.w;
        h[4] = (_Float16)hi.x; h[5] = (_Float16)hi.y;
        h[6] = (_Float16)hi.z; h[7] = (_Float16)hi.w;
        a[s] = h;
    }

    f32x4 acc[8];
#pragma unroll
    for (int t = 0; t < 8; t++) acc[t] = (f32x4){0.f, 0.f, 0.f, 0.f};

    const _Float16* wp = Wt + (size_t)q * 128 + 8 * g;
#pragma unroll
    for (int t = 0; t < 8; t++) {
#pragma unroll
        for (int s = 0; s < 4; s++) {
            half8 b = *(const half8*)(wp + (size_t)t * 2048 + 32 * s);
            acc[t] = __builtin_amdgcn_mfma_f32_16x16x32_f16(a[s], b, acc[t], 0, 0, 0);
        }
    }

#pragma unroll
    for (int j = 0; j < 4; j++) {
        int r = rowBase + 4 * g + j;          // C/D: row = 4*(l>>4)+reg, col = l&15
        float sc = dis ? dis[r] : 1.0f;
#pragma unroll
        for (int t = 0; t < 4; t++) {
            unsigned u = f2bf(acc[t][j] * sc) | (f2bf(acc[t + 4][j] * sc) << 16);
            hbU[(size_t)r * 64 + 16 * t + q] = u;
        }
    }
}

// ---- P1: gemm1 (vb < MF_BLOCKS) + XCD-windowed bucket fill. Window = vb&7:
// under grid-stride (+1024, 1024%8==0) vb&7 == physical bid&7 -> consistent
// per-XCD 3.2 MB adj2 slice (R5-proven). Coverage of every (window,chunk) pair
// is exact regardless of the real block->XCD mapping (perf heuristic only).
__device__ __forceinline__ void p1_body(int vb, int tx, const float* __restrict__ x,
                                        const _Float16* __restrict__ Wt0,
                                        unsigned* __restrict__ hbU,
                                        const int* __restrict__ ei,
                                        int* __restrict__ cnt,
                                        int* __restrict__ adj2) {
    if (vb < MF_BLOCKS) {
        gemm_mfma_body((vb * 4 + (tx >> 6)) * 16, x, 128, Wt0, nullptr, hbU);
    } else {
        int fid = vb - MF_BLOCKS;
        int xcd = vb & 7;
        int chunk = fid >> 3;
        int lo = xcd * XRANGE, hi = lo + XRANGE;
        int base = chunk * FILL_CHUNK + tx;
        int c[8], r[8];
#pragma unroll
        for (int j = 0; j < 8; j++) {
            int e = base + 256 * j;
            c[j] = (e < N_EDGES) ? ei[N_EDGES + e] : -1;
            r[j] = (e < N_EDGES) ? ei[e] : 0;
        }
#pragma unroll
        for (int j = 0; j < 8; j++) {
            if (c[j] >= lo && c[j] < hi) {
                int pos = atomicAdd(&cnt[c[j]], 1);
                if (pos < CAP) adj2[c[j] * CAP + pos] = r[j];
            }
        }
    }
}

// ---- agg core (R8-proven readlane pipeline; R10 lesson: per-edge rsqrtf is a
// 20-op precise chain that stalls the gather stream -> keep precomputed dis[]).
// wdis != nullptr (layer 1): rows unscaled, acc += dis[s]*h_s (s uniform ->
// dis[s] s_load). wdis == nullptr (layer 2): rows prescaled, pure add.
__device__ __forceinline__ void agg_core2(const unsigned* __restrict__ hb,
                                          const float* __restrict__ wdis,
                                          int node, int av, int deg, unsigned sv,
                                          float selfw, int lane,
                                          float& outL, float& outH) {
    float aL[4], aH[4];
    aL[0] = selfw * bflo(sv); aH[0] = selfw * bfhi(sv);
    aL[1] = aL[2] = aL[3] = 0.f;
    aH[1] = aH[2] = aH[3] = 0.f;

    if (deg > 0) {
        unsigned vA[8];
        float wA[8];
        int baseA = 0;
#pragma unroll
        for (int j = 0; j < 8; j++) {
            int s = (j < deg) ? __builtin_amdgcn_readlane(av, j) : node;
            vA[j] = hb[(size_t)s * 64 + lane];
            if (wdis) wA[j] = wdis[s];
        }
        int nbt = (deg + 7) >> 3;
        for (int b = 1; b < nbt; b++) {
            unsigned vB[8];
            float wB[8];
            int baseB = b << 3;
#pragma unroll
            for (int j = 0; j < 8; j++) {
                int e = baseB + j;
                int s = (e < deg) ? __builtin_amdgcn_readlane(av, e) : node;
                vB[j] = hb[(size_t)s * 64 + lane];
                if (wdis) wB[j] = wdis[s];
            }
#pragma unroll
            for (int j = 0; j < 8; j++) {
                if (wdis) {
                    aL[j & 3] = fmaf(wA[j], bflo(vA[j]), aL[j & 3]);
                    aH[j & 3] = fmaf(wA[j], bfhi(vA[j]), aH[j & 3]);
                } else {
                    aL[j & 3] += bflo(vA[j]);
                    aH[j & 3] += bfhi(vA[j]);
                }
            }
#pragma unroll
            for (int j = 0; j < 8; j++) { vA[j] = vB[j]; if (wdis) wA[j] = wB[j]; }
            baseA = baseB;
        }
#pragma unroll
        for (int j = 0; j < 8; j++) {
            float xx = (baseA + j < deg) ? bflo(vA[j]) : 0.f;
            float yy = (baseA + j < deg) ? bfhi(vA[j]) : 0.f;
            if (wdis) {
                aL[j & 3] = fmaf(wA[j], xx, aL[j & 3]);
                aH[j & 3] = fmaf(wA[j], yy, aH[j & 3]);
            } else {
                aL[j & 3] += xx;
                aH[j & 3] += yy;
            }
        }
    }
    outL = (aL[0] + aL[1]) + (aL[2] + aL[3]);
    outH = (aH[0] + aH[1]) + (aH[2] + aH[3]);
}

// ---- P3: agg1 + gemm2 (R8-proven). 16 nodes/vb; h1 -> feat & LDS; MFMA from LDS
// -> hb2 (distinct buffer). Trailing __syncthreads so the next grid-stride
// iteration can safely rewrite Hs.
__device__ __forceinline__ void agg_gemm_body(int vb, _Float16 (*Hs)[136],
                                              const unsigned* __restrict__ hb,
                                              const float* __restrict__ dis,
                                              const int* __restrict__ cnt,
                                              const int* __restrict__ adj2,
                                              const float* __restrict__ bias,
                                              const _Float16* __restrict__ Wt,
                                              float* __restrict__ out,
                                              unsigned* __restrict__ hb2) {
    int w = threadIdx.x >> 6;
    int lane = threadIdx.x & 63;
    int rowBase = vb * 16;
    int nb = rowBase + w * 4;

    int av[4], deg[4];
    unsigned sv[4];
#pragma unroll
    for (int i = 0; i < 4; i++) av[i] = adj2[(nb + i) * CAP + lane];
#pragma unroll
    for (int i = 0; i < 4; i++) sv[i] = hb[(size_t)(nb + i) * 64 + lane];
#pragma unroll
    for (int i = 0; i < 4; i++) {
        int d = __builtin_amdgcn_readfirstlane(cnt[nb + i]);
        deg[i] = (d > CAP) ? CAP : d;
    }

#pragma unroll
    for (int i = 0; i < 4; i++) {
        int node = nb + i;
        float dc = dis[node];
        float sL, sH;
        agg_core2(hb, dis, node, av[i], deg[i], sv[i], dc, lane, sL, sH);
        float r0 = fmaxf(fmaf(dc, sL, bias[lane]), 0.f);
        float r1 = fmaxf(fmaf(dc, sH, bias[lane + 64]), 0.f);
        out[(size_t)node * 296 + lane] = r0;
        out[(size_t)node * 296 + 64 + lane] = r1;
        Hs[w * 4 + i][lane] = (_Float16)r0;
        Hs[w * 4 + i][lane + 64] = (_Float16)r1;
    }
    __syncthreads();

    int q = lane & 15, g = lane >> 4;
    half8 a[4];
#pragma unroll
    for (int s = 0; s < 4; s++) a[s] = *(const half8*)&Hs[q][8 * g + 32 * s];

    f32x4 acc0 = (f32x4){0.f, 0.f, 0.f, 0.f};
    f32x4 acc1 = (f32x4){0.f, 0.f, 0.f, 0.f};
    const _Float16* wp = Wt + (size_t)q * 128 + 8 * g;
#pragma unroll
    for (int s = 0; s < 4; s++) {
        half8 bA = *(const half8*)(wp + (size_t)w * 2048 + 32 * s);
        half8 bB = *(const half8*)(wp + (size_t)(w + 4) * 2048 + 32 * s);
        acc0 = __builtin_amdgcn_mfma_f32_16x16x32_f16(a[s], bA, acc0, 0, 0, 0);
        acc1 = __builtin_amdgcn_mfma_f32_16x16x32_f16(a[s], bB, acc1, 0, 0, 0);
    }
#pragma unroll
    for (int j = 0; j < 4; j++) {
        int r = rowBase + 4 * g + j;
        float sc = dis[r];
        unsigned u = f2bf(acc0[j] * sc) | (f2bf(acc1[j] * sc) << 16);
        hb2[(size_t)r * 64 + 16 * w + q] = u;
    }
    __syncthreads();
}

// ---- P4: agg2 + classifier (R8-proven). hb2 prescaled -> pure-add agg;
// waves 0..2 do the 3 NC col-tiles from LDS; logits + feat tail.
__device__ __forceinline__ void agg_cls_body(int vb, _Float16 (*Hs)[136],
                                             const unsigned* __restrict__ hb2,
                                             const float* __restrict__ dis,
                                             const int* __restrict__ cnt,
                                             const int* __restrict__ adj2,
                                             const float* __restrict__ bias,
                                             const _Float16* __restrict__ Wtc,
                                             const float* __restrict__ bc,
                                             float* __restrict__ feat,
                                             float* __restrict__ logits) {
    int w = threadIdx.x >> 6;
    int lane = threadIdx.x & 63;
    int rowBase = vb * 16;
    int nb = rowBase + w * 4;

    int av[4], deg[4];
    unsigned sv[4];
#pragma unroll
    for (int i = 0; i < 4; i++) av[i] = adj2[(nb + i) * CAP + lane];
#pragma unroll
    for (int i = 0; i < 4; i++) sv[i] = hb2[(size_t)(nb + i) * 64 + lane];
#pragma unroll
    for (int i = 0; i < 4; i++) {
        int d = __builtin_amdgcn_readfirstlane(cnt[nb + i]);
        deg[i] = (d > CAP) ? CAP : d;
    }

#pragma unroll
    for (int i = 0; i < 4; i++) {
        int node = nb + i;
        float sL, sH;
        agg_core2(hb2, nullptr, node, av[i], deg[i], sv[i], 1.0f, lane, sL, sH);
        float dc = dis[node];
        float r0 = fmaxf(fmaf(dc, sL, bias[lane]), 0.f);
        float r1 = fmaxf(fmaf(dc, sH, bias[lane + 64]), 0.f);
        feat[(size_t)node * 296 + 128 + lane] = r0;
        feat[(size_t)node * 296 + 192 + lane] = r1;
        Hs[w * 4 + i][lane] = (_Float16)r0;
        Hs[w * 4 + i][lane + 64] = (_Float16)r1;
    }
    __syncthreads();

    if (w < 3) {
        int q = lane & 15, g = lane >> 4;
        half8 a[4];
#pragma unroll
        for (int s = 0; s < 4; s++) a[s] = *(const half8*)&Hs[q][8 * g + 32 * s];

        f32x4 acc = (f32x4){0.f, 0.f, 0.f, 0.f};
        const _Float16* wp = Wtc + (size_t)(16 * w + q) * 128 + 8 * g;
#pragma unroll
        for (int s = 0; s < 4; s++) {
            half8 b = *(const half8*)(wp + 32 * s);
            acc = __builtin_amdgcn_mfma_f32_16x16x32_f16(a[s], b, acc, 0, 0, 0);
        }
        int c = 16 * w + q;
        if (c < NC) {
#pragma unroll
            for (int j = 0; j < 4; j++) {
                int r = rowBase + 4 * g + j;
                float v = acc[j] + bc[c];
                logits[(size_t)r * NC + c] = v;
                feat[(size_t)r * 296 + 256 + c] = v;
            }
        }
    }
    __syncthreads();
}

// ================= single cooperative kernel: 5 phases, 4 grid syncs ============
// Replaces 5 dispatches (+ their ~20 us boundaries) with in-kernel grid.sync().
// COOP_GRID=1024 = 4 blocks/CU co-resident (16 waves/CU == measured per-phase
// occupancy, so phase throughput is preserved). launch_bounds(256,4) caps VGPR
// at 128 (phase max ~64 -> no spill).

__global__ __launch_bounds__(256, 4) void mega_kernel(
        const float* __restrict__ x, const int* __restrict__ ei,
        const float* __restrict__ w0, const float* __restrict__ b0,
        const float* __restrict__ w1, const float* __restrict__ b1,
        const float* __restrict__ cls_w, const float* __restrict__ cls_b,
        _Float16* __restrict__ Wt0, _Float16* __restrict__ Wt1,
        _Float16* __restrict__ Wtc, int* __restrict__ cnt,
        float* __restrict__ dis, int* __restrict__ adj2,
        unsigned* __restrict__ hbU, unsigned* __restrict__ hbU2,
        float* __restrict__ feat, float* __restrict__ logits) {
    __shared__ _Float16 Hs[16][136];
    cg::grid_group grid = cg::this_grid();
    int tx = threadIdx.x;
    int bid = blockIdx.x;

    // P0: weight transpose + cnt zero
    if (bid < PREP_BLOCKS) prep_body(bid, tx, w0, w1, cls_w, Wt0, Wt1, Wtc, cnt);
    grid.sync();

    // P1: gemm1 + bucket fill
    for (int vb = bid; vb < MF_BLOCKS + FILL_BLOCKS; vb += COOP_GRID)
        p1_body(vb, tx, x, Wt0, hbU, ei, cnt, adj2);
    grid.sync();

    // P2: dis = rsqrt(deg+1)
    {
        int i = bid * 256 + tx;
        if (i < N_NODES) dis[i] = rsqrtf((float)cnt[i] + 1.0f);
    }
    grid.sync();

    // P3: agg1 + gemm2 -> hb2
    for (int vb = bid; vb < FB_BLOCKS; vb += COOP_GRID)
        agg_gemm_body(vb, Hs, hbU, dis, cnt, adj2, b0, Wt1, feat, hbU2);
    grid.sync();

    // P4: agg2 + classifier
    for (int vb = bid; vb < FB_BLOCKS; vb += COOP_GRID)
        agg_cls_body(vb, Hs, hbU2, dis, cnt, adj2, b1, Wtc, cls_b, feat, logits);
}

// ================= classic fallback kernels (R8-proven chain) ===================

__global__ __launch_bounds__(256) void prep_w_kernel(const float* __restrict__ w0,
                                                     const float* __restrict__ w1,
                                                     const float* __restrict__ wc,
                                                     _Float16* __restrict__ Wt0,
                                                     _Float16* __restrict__ Wt1,
                                                     _Float16* __restrict__ Wtc,
                                                     int* __restrict__ cnt) {
    prep_body(blockIdx.x, threadIdx.x, w0, w1, wc, Wt0, Wt1, Wtc, cnt);
}

__global__ __launch_bounds__(256) void gemm_fill_kernel(const float* __restrict__ x,
                                                        const _Float16* __restrict__ Wt0,
                                                        unsigned* __restrict__ hbU,
                                                        const int* __restrict__ ei,
                                                        int* __restrict__ cnt,
                                                        int* __restrict__ adj2) {
    p1_body(blockIdx.x, threadIdx.x, x, Wt0, hbU, ei, cnt, adj2);
}

__global__ __launch_bounds__(256) void dis_kernel(const int* __restrict__ cnt,
                                                  float* __restrict__ dis) {
    int i = blockIdx.x * 256 + threadIdx.x;
    if (i < N_NODES) dis[i] = rsqrtf((float)cnt[i] + 1.0f);
}

__global__ __launch_bounds__(256) void agg_gemm_kernel(const unsigned* __restrict__ hb,
                                                       const float* __restrict__ dis,
                                                       const int* __restrict__ cnt,
                                                       const int* __restrict__ adj2,
                                                       const float* __restrict__ bias,
                                                       const _Float16* __restrict__ Wt,
                                                       float* __restrict__ out,
                                                       unsigned* __restrict__ hb2) {
    __shared__ _Float16 Hs[16][136];
    agg_gemm_body(blockIdx.x, Hs, hb, dis, cnt, adj2, bias, Wt, out, hb2);
}

__global__ __launch_bounds__(256) void agg_cls_kernel(const unsigned* __restrict__ hb2,
                                                      const float* __restrict__ dis,
                                                      const int* __restrict__ cnt,
                                                      const int* __restrict__ adj2,
                                                      const float* __restrict__ bias,
                                                      const _Float16* __restrict__ Wtc,
                                                      const float* __restrict__ bc,
                                                      float* __restrict__ feat,
                                                      float* __restrict__ logits) {
    __shared__ _Float16 Hs[16][136];
    agg_cls_body(blockIdx.x, Hs, hb2, dis, cnt, adj2, bias, Wtc, bc, feat, logits);
}

// small-ws fallback: standalone agg1 + in-place gemm2
__global__ __launch_bounds__(256) void agg_kernel(const unsigned* __restrict__ hb,
                                                  const float* __restrict__ dis,
                                                  const int* __restrict__ cnt,
                                                  const int* __restrict__ adj2,
                                                  const float* __restrict__ bias,
                                                  float* __restrict__ out, int ldo) {
    int node = __builtin_amdgcn_readfirstlane(blockIdx.x * 4 + (threadIdx.x >> 6));
    int lane = threadIdx.x & 63;
    int av = adj2[node * CAP + lane];
    unsigned sv = hb[(size_t)node * 64 + lane];
    int deg = __builtin_amdgcn_readfirstlane(cnt[node]);
    if (deg > CAP) deg = CAP;
    float dc = dis[node];
    float sL, sH;
    agg_core2(hb, dis, node, av, deg, sv, dc, lane, sL, sH);
    out[(size_t)node * ldo + lane] = fmaxf(fmaf(dc, sL, bias[lane]), 0.f);
    out[(size_t)node * ldo + 64 + lane] = fmaxf(fmaf(dc, sH, bias[lane + 64]), 0.f);
}

__global__ __launch_bounds__(256) void gemm_mfma_kernel(const float* __restrict__ A, int lda,
                                                        const _Float16* __restrict__ Wt,
                                                        const float* __restrict__ dis,
                                                        unsigned* __restrict__ hbU) {
    int rowBase = (blockIdx.x * 4 + (int)(threadIdx.x >> 6)) * 16;
    gemm_mfma_body(rowBase, A, lda, Wt, dis, hbU);
}

// ---------------- launch ----------------

extern "C" void kernel_launch(void* const* d_in, const int* in_sizes, int n_in,
                              void* d_out, int out_size, void* d_ws, size_t ws_size,
                              hipStream_t stream) {
    (void)in_sizes; (void)n_in; (void)out_size;

    const float* x     = (const float*)d_in[0];
    const int*   ei    = (const int*)d_in[1];
    const float* w0    = (const float*)d_in[2];
    const float* b0    = (const float*)d_in[3];
    const float* w1    = (const float*)d_in[4];
    const float* b1    = (const float*)d_in[5];
    const float* cls_w = (const float*)d_in[6];
    const float* cls_b = (const float*)d_in[7];

    float* logits = (float*)d_out;
    float* feat   = logits + (size_t)N_NODES * NC;   // [N,296]: h1 | h2 | logits

    char* ws = (char*)d_ws;
    int*       cnt  = (int*)(ws + 0);                 // 400 KB
    float*     dis  = (float*)(ws + 400000);          // 400 KB
    int*       adj2 = (int*)(ws + 800000);            // 25.6 MB (100K x 64)
    unsigned*  hbU  = (unsigned*)(ws + 26400000);     // 25.6 MB bf16-pair matrix
    _Float16*  Wt0  = (_Float16*)(ws + 52000000);     // 32 KB
    _Float16*  Wt1  = (_Float16*)(ws + 52032768);     // 32 KB
    _Float16*  Wtc  = (_Float16*)(ws + 52065536);     // 12 KB
    const size_t HB2_OFF = 52080000;                  // 16B-aligned
    const size_t NEEDED  = HB2_OFF + (size_t)N_NODES * 256;   // 77.68 MB
    bool big = (ws_size >= NEEDED);
    unsigned* hbU2 = big ? (unsigned*)(ws + HB2_OFF) : hbU;

    if (big) {
        void* args[] = {&x, &ei, &w0, &b0, &w1, &b1, &cls_w, &cls_b,
                        &Wt0, &Wt1, &Wtc, &cnt, &dis, &adj2, &hbU, &hbU2,
                        &feat, &logits};
        hipError_t st = hipLaunchCooperativeKernel((const void*)mega_kernel,
                                                   dim3(COOP_GRID), dim3(256),
                                                   args, 0, stream);
        if (st == hipSuccess) return;
        // else fall through to the classic dispatch chain
    }

    prep_w_kernel<<<PREP_BLOCKS, 256, 0, stream>>>(w0, w1, cls_w, Wt0, Wt1, Wtc, cnt);
    gemm_fill_kernel<<<MF_BLOCKS + FILL_BLOCKS, 256, 0, stream>>>(
        x, Wt0, hbU, ei, cnt, adj2);
    dis_kernel<<<(N_NODES + 255) / 256, 256, 0, stream>>>(cnt, dis);

    if (big) {
        agg_gemm_kernel<<<FB_BLOCKS, 256, 0, stream>>>(hbU, dis, cnt, adj2, b0, Wt1,
                                                       feat, hbU2);
        agg_cls_kernel<<<FB_BLOCKS, 256, 0, stream>>>(hbU2, dis, cnt, adj2, b1, Wtc,
                                                      cls_b, feat, logits);
    } else {
        agg_kernel<<<N_NODES / 4, 256, 0, stream>>>(hbU, dis, cnt, adj2, b0,
                                                    feat + 0, 296);
        gemm_mfma_kernel<<<MF_BLOCKS, 256, 0, stream>>>(feat, 296, Wt1, dis, hbU);
        agg_cls_kernel<<<FB_BLOCKS, 256, 0, stream>>>(hbU, dis, cnt, adj2, b1, Wtc,
                                                      cls_b, feat, logits);
    }
}

// Round 12
// 438.307 us; speedup vs baseline: 2.0887x; 2.0887x over previous
//
#include <hip/hip_runtime.h>
#include <hip/hip_bf16.h>

#define N_NODES 100000
#define N_EDGES 1600000
#define NC 40
#define CAP 64               // bucket capacity; data max-degree ~45 << 64

#define NXCD 8
#define XRANGE 12500         // N_NODES / NXCD : destination slice per XCD
#define FILL_CHUNK  2048     // edges per block (256 thr x 8)
#define FILL_CHUNKS 782      // ceil(N_EDGES/FILL_CHUNK)
#define FILL_BLOCKS (NXCD * FILL_CHUNKS)   // 6256  (R5-proven 8-window config)
#define MF_BLOCKS 1563       // ceil(100000 / 64): 64 rows/block = 4 waves x 16 rows
#define FB_BLOCKS 6250       // fused agg blocks: 16 nodes each (100000/16)

typedef _Float16 half8 __attribute__((ext_vector_type(8)));
typedef float f32x4 __attribute__((ext_vector_type(4)));

// ---- bf16 helpers (packed 2x16 in a uint) ----
__device__ __forceinline__ float bflo(unsigned u) { return __uint_as_float(u << 16); }
__device__ __forceinline__ float bfhi(unsigned u) { return __uint_as_float(u & 0xffff0000u); }
__device__ __forceinline__ unsigned f2bf(float f) {
    unsigned u = __float_as_uint(f);
    return (u + 0x7fffu + ((u >> 16) & 1u)) >> 16;
}

// ---------------- W prep (+ cnt zeroing, replaces the memset dispatch) -----------
// blocks 0-7: w0 (128x128 -> 8 x 2048), 8-15: w1, 16-18: wtc (48x128 = 6144),
// blocks 19-116: zero cnt (98 x 256 thr; 25000 int4s exactly).

__global__ __launch_bounds__(256) void prep_w_kernel(const float* __restrict__ w0,
                                                     const float* __restrict__ w1,
                                                     const float* __restrict__ wc,
                                                     _Float16* __restrict__ Wt0,
                                                     _Float16* __restrict__ Wt1,
                                                     _Float16* __restrict__ Wtc,
                                                     int* __restrict__ cnt) {
    int tx = threadIdx.x;
    int b = blockIdx.x;
    if (b < 16) {
        const float* W = (b >= 8) ? w1 : w0;
        _Float16* T = (b >= 8) ? Wt1 : Wt0;
        int base = (b & 7) * 2048;
#pragma unroll
        for (int i = 0; i < 8; i++) {
            int e = base + tx + 256 * i;   // output index n*128+k (coalesced writes)
            int n = e >> 7, k = e & 127;   // e < 16384 -> n < 128
            T[e] = (_Float16)W[k * 128 + n];
        }
    } else if (b < 19) {
        // cls_w [128][40] -> Wtc [48][128], zero-padded cols 40..47
        int base = (b - 16) * 2048;
#pragma unroll
        for (int i = 0; i < 8; i++) {
            int e = base + tx + 256 * i;   // e < 6144 -> n < 48
            int n = e >> 7, k = e & 127;
            Wtc[e] = (_Float16)((n < NC) ? wc[k * NC + n] : 0.f);
        }
    } else {
        int t4 = (b - 19) * 256 + tx;      // 100000/4 = 25000 int4s exactly
        if (t4 < 25000) ((int4*)cnt)[t4] = make_int4(0, 0, 0, 0);
    }
}

// ---------------- MFMA fp16 GEMM body: hb = bf16((A @ W) [* dis]) ----------------
// Per wave: 16 rows x 128 cols. A-frag: lane holds A[rowBase + (l&15)][8*(l>>4)+i],
// W-frag: Wt[16*t + (l&15)][same k slots]. A/B share one slot->k bijection, so the
// result is layout-map invariant; C/D layout per learn_hip m89.
// hb pair layout: uint at [r*64 + c] = features (c, c+64) of row r.
// dis == nullptr -> unscaled (layer 1; dis unknown while fill runs concurrently).
// A rows are read ONCE -> non-temporal loads keep L2 for reused data (Wt, adj2).

__device__ __forceinline__ void gemm_mfma_body(int rowBase, const float* __restrict__ A,
                                               int lda, const _Float16* __restrict__ Wt,
                                               const float* __restrict__ dis,
                                               unsigned* __restrict__ hbU) {
    if (rowBase >= N_NODES) return;
    int lane = threadIdx.x & 63;
    int q = lane & 15, g = lane >> 4;

    const float* ap = A + (size_t)(rowBase + q) * lda + 8 * g;
    half8 a[4];
#pragma unroll
    for (int s = 0; s < 4; s++) {
        f32x4 lo = __builtin_nontemporal_load((const f32x4*)(ap + 32 * s));
        f32x4 hi = __builtin_nontemporal_load((const f32x4*)(ap + 32 * s + 4));
        half8 h;
        h[0] = (_Float16)lo[0]; h[1] = (_Float16)lo[1];
        h[2] = (_Float16)lo[2]; h[3] = (_Float16)lo[3];
        h[4] = (_Float16)hi[0]; h[5] = (_Float16)hi[1];
        h[6] = (_Float16)hi[2]; h[7] = (_Float16)hi[3];
        a[s] = h;
    }

    f32x4 acc[8];
#pragma unroll
    for (int t = 0; t < 8; t++) acc[t] = (f32x4){0.f, 0.f, 0.f, 0.f};

    const _Float16* wp = Wt + (size_t)q * 128 + 8 * g;
#pragma unroll
    for (int t = 0; t < 8; t++) {
#pragma unroll
        for (int s = 0; s < 4; s++) {
            half8 b = *(const half8*)(wp + (size_t)t * 2048 + 32 * s);
            acc[t] = __builtin_amdgcn_mfma_f32_16x16x32_f16(a[s], b, acc[t], 0, 0, 0);
        }
    }

#pragma unroll
    for (int j = 0; j < 4; j++) {
        int r = rowBase + 4 * g + j;          // C/D: row = 4*(l>>4)+reg, col = l&15
        float sc = dis ? dis[r] : 1.0f;
#pragma unroll
        for (int t = 0; t < 4; t++) {
            unsigned u = f2bf(acc[t][j] * sc) | (f2bf(acc[t + 4][j] * sc) << 16);
            hbU[(size_t)r * 64 + 16 * t + q] = u;
        }
    }
}

// ---------------- fused: MFMA gemm1 + XCD-windowed bucket fill (R5-proven) --------
// Fill block handles destination range (bid&7)*XRANGE: dispatch round-robins blocks
// over the 8 XCDs, so each XCD writes only its own 3.2 MB adj2 slice (< 4 MB L2)
// -> partial-line scatter writes merge in L2. Any (xcd,chunk) pair occurs exactly
// once -> correctness independent of actual block->XCD mapping.
// ei is a read-once stream (8x replay, never L2-reusable at 12.8 MB > 4 MB) ->
// NON-TEMPORAL loads so it stops evicting the adj2 merge window (R11 theory:
// this eviction is why WRITE_SIZE was 104 MB vs ~52 ideal).

__global__ __launch_bounds__(256) void gemm_fill_kernel(const float* __restrict__ x,
                                                        const _Float16* __restrict__ Wt0,
                                                        unsigned* __restrict__ hbU,
                                                        const int* __restrict__ ei,
                                                        int* __restrict__ cnt,
                                                        int* __restrict__ adj2) {
    int tx = threadIdx.x;
    if (blockIdx.x < MF_BLOCKS) {
        int rowBase = (blockIdx.x * 4 + (tx >> 6)) * 16;
        gemm_mfma_body(rowBase, x, 128, Wt0, nullptr, hbU);
    } else {
        int fid = blockIdx.x - MF_BLOCKS;
        int xcd = blockIdx.x & 7;            // bind dest window to (heuristic) HW XCD
        int chunk = fid >> 3;
        int lo = xcd * XRANGE, hi = lo + XRANGE;
        int base = chunk * FILL_CHUNK + tx;
        int c[8], r[8];
#pragma unroll
        for (int j = 0; j < 8; j++) {
            int e = base + 256 * j;
            c[j] = (e < N_EDGES) ? __builtin_nontemporal_load(&ei[N_EDGES + e]) : -1;
            r[j] = (e < N_EDGES) ? __builtin_nontemporal_load(&ei[e]) : 0;
        }
#pragma unroll
        for (int j = 0; j < 8; j++) {
            if (c[j] >= lo && c[j] < hi) {
                int pos = atomicAdd(&cnt[c[j]], 1);
                if (pos < CAP) adj2[c[j] * CAP + pos] = r[j];
            }
        }
    }
}

// ---------------- dis = rsqrt(deg+1) (hb stays UNSCALED for layer 1) -------------

__global__ __launch_bounds__(256) void dis_kernel(const int* __restrict__ cnt,
                                                  float* __restrict__ dis) {
    int i = blockIdx.x * 256 + threadIdx.x;
    if (i < N_NODES) dis[i] = rsqrtf((float)cnt[i] + 1.0f);
}

// ---------------- agg core (R8-proven readlane pipeline) ----------------
// R9/R10 lessons: scalar bucket walk serializes the gather stream (113->121);
// per-edge rsqrtf is a 20-op precise chain that halves gather BW (113->215).
// Keep readlane extraction + precomputed dis[]. wdis != nullptr (layer 1):
// rows unscaled, acc += dis[s]*h_s (s uniform -> dis[s] s_load). wdis == nullptr
// (layer 2): rows prescaled, pure add. Branch folds at inline site.

__device__ __forceinline__ void agg_core2(const unsigned* __restrict__ hb,
                                          const float* __restrict__ wdis,
                                          int node, int av, int deg, unsigned sv,
                                          float selfw, int lane,
                                          float& outL, float& outH) {
    float aL[4], aH[4];
    aL[0] = selfw * bflo(sv); aH[0] = selfw * bfhi(sv);
    aL[1] = aL[2] = aL[3] = 0.f;
    aH[1] = aH[2] = aH[3] = 0.f;

    if (deg > 0) {
        unsigned vA[8];
        float wA[8];
        int baseA = 0;
#pragma unroll
        for (int j = 0; j < 8; j++) {
            int s = (j < deg) ? __builtin_amdgcn_readlane(av, j) : node;
            vA[j] = hb[(size_t)s * 64 + lane];
            if (wdis) wA[j] = wdis[s];
        }
        int nbt = (deg + 7) >> 3;
        for (int b = 1; b < nbt; b++) {
            unsigned vB[8];
            float wB[8];
            int baseB = b << 3;
#pragma unroll
            for (int j = 0; j < 8; j++) {
                int e = baseB + j;
                int s = (e < deg) ? __builtin_amdgcn_readlane(av, e) : node;
                vB[j] = hb[(size_t)s * 64 + lane];
                if (wdis) wB[j] = wdis[s];
            }
            // batch b-1 is always full (b-1 < nbt-1  =>  8b <= deg)
#pragma unroll
            for (int j = 0; j < 8; j++) {
                if (wdis) {
                    aL[j & 3] = fmaf(wA[j], bflo(vA[j]), aL[j & 3]);
                    aH[j & 3] = fmaf(wA[j], bfhi(vA[j]), aH[j & 3]);
                } else {
                    aL[j & 3] += bflo(vA[j]);
                    aH[j & 3] += bfhi(vA[j]);
                }
            }
#pragma unroll
            for (int j = 0; j < 8; j++) { vA[j] = vB[j]; if (wdis) wA[j] = wB[j]; }
            baseA = baseB;
        }
#pragma unroll
        for (int j = 0; j < 8; j++) {
            float xx = (baseA + j < deg) ? bflo(vA[j]) : 0.f;
            float yy = (baseA + j < deg) ? bfhi(vA[j]) : 0.f;
            if (wdis) {
                aL[j & 3] = fmaf(wA[j], xx, aL[j & 3]);
                aH[j & 3] = fmaf(wA[j], yy, aH[j & 3]);
            } else {
                aL[j & 3] += xx;
                aH[j & 3] += yy;
            }
        }
    }
    outL = (aL[0] + aL[1]) + (aL[2] + aL[3]);
    outH = (aH[0] + aH[1]) + (aH[2] + aH[3]);
}

// ---------------- fused agg1 + gemm2: h1 = relu(dc*sum+b0) -> feat & LDS;
// then hb2 = bf16(dis * (h1 @ W1)) straight from LDS. Block = 16 nodes
// (4 waves x 4 sequential aggs, setup loads hoisted). LDS row padded to 136
// halves (2-way bank aliasing = free). Wave w computes col-tiles {w, w+4}.
// hb2 distinct from hb (other blocks still gather hb concurrently).
// adj2 reads + feat writes are read/write-once -> non-temporal (keep L2 for hb).

__global__ __launch_bounds__(256) void agg_gemm_kernel(const unsigned* __restrict__ hb,
                                                       const float* __restrict__ dis,
                                                       const int* __restrict__ cnt,
                                                       const int* __restrict__ adj2,
                                                       const float* __restrict__ bias,
                                                       const _Float16* __restrict__ Wt,
                                                       float* __restrict__ out,
                                                       unsigned* __restrict__ hb2) {
    __shared__ _Float16 Hs[16][136];
    int w = threadIdx.x >> 6;
    int lane = threadIdx.x & 63;
    int rowBase = blockIdx.x * 16;
    int nb = rowBase + w * 4;

    int av[4], deg[4];
    unsigned sv[4];
#pragma unroll
    for (int i = 0; i < 4; i++)
        av[i] = __builtin_nontemporal_load(&adj2[(nb + i) * CAP + lane]);
#pragma unroll
    for (int i = 0; i < 4; i++) sv[i] = hb[(size_t)(nb + i) * 64 + lane];
#pragma unroll
    for (int i = 0; i < 4; i++) {
        int d = __builtin_amdgcn_readfirstlane(cnt[nb + i]);
        deg[i] = (d > CAP) ? CAP : d;
    }

#pragma unroll
    for (int i = 0; i < 4; i++) {
        int node = nb + i;
        float dc = dis[node];
        float sL, sH;
        agg_core2(hb, dis, node, av[i], deg[i], sv[i], dc, lane, sL, sH);
        float r0 = fmaxf(fmaf(dc, sL, bias[lane]), 0.f);
        float r1 = fmaxf(fmaf(dc, sH, bias[lane + 64]), 0.f);
        __builtin_nontemporal_store(r0, &out[(size_t)node * 296 + lane]);
        __builtin_nontemporal_store(r1, &out[(size_t)node * 296 + 64 + lane]);
        Hs[w * 4 + i][lane] = (_Float16)r0;
        Hs[w * 4 + i][lane + 64] = (_Float16)r1;
    }
    __syncthreads();

    int q = lane & 15, g = lane >> 4;
    half8 a[4];
#pragma unroll
    for (int s = 0; s < 4; s++) a[s] = *(const half8*)&Hs[q][8 * g + 32 * s];

    f32x4 acc0 = (f32x4){0.f, 0.f, 0.f, 0.f};
    f32x4 acc1 = (f32x4){0.f, 0.f, 0.f, 0.f};
    const _Float16* wp = Wt + (size_t)q * 128 + 8 * g;
#pragma unroll
    for (int s = 0; s < 4; s++) {
        half8 bA = *(const half8*)(wp + (size_t)w * 2048 + 32 * s);
        half8 bB = *(const half8*)(wp + (size_t)(w + 4) * 2048 + 32 * s);
        acc0 = __builtin_amdgcn_mfma_f32_16x16x32_f16(a[s], bA, acc0, 0, 0, 0);
        acc1 = __builtin_amdgcn_mfma_f32_16x16x32_f16(a[s], bB, acc1, 0, 0, 0);
    }
#pragma unroll
    for (int j = 0; j < 4; j++) {
        int r = rowBase + 4 * g + j;
        float sc = dis[r];
        unsigned u = f2bf(acc0[j] * sc) | (f2bf(acc1[j] * sc) << 16);
        hb2[(size_t)r * 64 + 16 * w + q] = u;
    }
}

// ---------------- fused agg2 + classifier ----------------
// hb2 prescaled -> pure-add agg (wdis=nullptr, selfw=1). h2 -> feat[128..256) & LDS;
// waves 0..2 each do one 16-col NC-tile of the classifier from LDS; logits + tail.

__global__ __launch_bounds__(256) void agg_cls_kernel(const unsigned* __restrict__ hb2,
                                                      const float* __restrict__ dis,
                                                      const int* __restrict__ cnt,
                                                      const int* __restrict__ adj2,
                                                      const float* __restrict__ bias,
                                                      const _Float16* __restrict__ Wtc,
                                                      const float* __restrict__ bc,
                                                      float* __restrict__ feat,
                                                      float* __restrict__ logits) {
    __shared__ _Float16 Hs[16][136];
    int w = threadIdx.x >> 6;
    int lane = threadIdx.x & 63;
    int rowBase = blockIdx.x * 16;
    int nb = rowBase + w * 4;

    int av[4], deg[4];
    unsigned sv[4];
#pragma unroll
    for (int i = 0; i < 4; i++)
        av[i] = __builtin_nontemporal_load(&adj2[(nb + i) * CAP + lane]);
#pragma unroll
    for (int i = 0; i < 4; i++) sv[i] = hb2[(size_t)(nb + i) * 64 + lane];
#pragma unroll
    for (int i = 0; i < 4; i++) {
        int d = __builtin_amdgcn_readfirstlane(cnt[nb + i]);
        deg[i] = (d > CAP) ? CAP : d;
    }

#pragma unroll
    for (int i = 0; i < 4; i++) {
        int node = nb + i;
        float sL, sH;
        agg_core2(hb2, nullptr, node, av[i], deg[i], sv[i], 1.0f, lane, sL, sH);
        float dc = dis[node];
        float r0 = fmaxf(fmaf(dc, sL, bias[lane]), 0.f);
        float r1 = fmaxf(fmaf(dc, sH, bias[lane + 64]), 0.f);
        __builtin_nontemporal_store(r0, &feat[(size_t)node * 296 + 128 + lane]);
        __builtin_nontemporal_store(r1, &feat[(size_t)node * 296 + 192 + lane]);
        Hs[w * 4 + i][lane] = (_Float16)r0;
        Hs[w * 4 + i][lane + 64] = (_Float16)r1;
    }
    __syncthreads();

    if (w < 3) {
        int q = lane & 15, g = lane >> 4;
        half8 a[4];
#pragma unroll
        for (int s = 0; s < 4; s++) a[s] = *(const half8*)&Hs[q][8 * g + 32 * s];

        f32x4 acc = (f32x4){0.f, 0.f, 0.f, 0.f};
        const _Float16* wp = Wtc + (size_t)(16 * w + q) * 128 + 8 * g;
#pragma unroll
        for (int s = 0; s < 4; s++) {
            half8 b = *(const half8*)(wp + 32 * s);
            acc = __builtin_amdgcn_mfma_f32_16x16x32_f16(a[s], b, acc, 0, 0, 0);
        }
        int c = 16 * w + q;
        if (c < NC) {
#pragma unroll
            for (int j = 0; j < 4; j++) {
                int r = rowBase + 4 * g + j;
                float v = acc[j] + bc[c];
                __builtin_nontemporal_store(v, &logits[(size_t)r * NC + c]);
                __builtin_nontemporal_store(v, &feat[(size_t)r * 296 + 256 + c]);
            }
        }
    }
}

// ---------------- small-ws fallback: standalone agg1 + in-place gemm2 ----------------

__global__ __launch_bounds__(256) void agg_kernel(const unsigned* __restrict__ hb,
                                                  const float* __restrict__ dis,
                                                  const int* __restrict__ cnt,
                                                  const int* __restrict__ adj2,
                                                  const float* __restrict__ bias,
                                                  float* __restrict__ out, int ldo) {
    int node = __builtin_amdgcn_readfirstlane(blockIdx.x * 4 + (threadIdx.x >> 6));
    int lane = threadIdx.x & 63;
    int av = adj2[node * CAP + lane];
    unsigned sv = hb[(size_t)node * 64 + lane];
    int deg = __builtin_amdgcn_readfirstlane(cnt[node]);
    if (deg > CAP) deg = CAP;
    float dc = dis[node];
    float sL, sH;
    agg_core2(hb, dis, node, av, deg, sv, dc, lane, sL, sH);
    out[(size_t)node * ldo + lane] = fmaxf(fmaf(dc, sL, bias[lane]), 0.f);
    out[(size_t)node * ldo + 64 + lane] = fmaxf(fmaf(dc, sH, bias[lane + 64]), 0.f);
}

__global__ __launch_bounds__(256) void gemm_mfma_kernel(const float* __restrict__ A, int lda,
                                                        const _Float16* __restrict__ Wt,
                                                        const float* __restrict__ dis,
                                                        unsigned* __restrict__ hbU) {
    int rowBase = (blockIdx.x * 4 + (int)(threadIdx.x >> 6)) * 16;
    gemm_mfma_body(rowBase, A, lda, Wt, dis, hbU);
}

// ---------------- launch ----------------

extern "C" void kernel_launch(void* const* d_in, const int* in_sizes, int n_in,
                              void* d_out, int out_size, void* d_ws, size_t ws_size,
                              hipStream_t stream) {
    (void)in_sizes; (void)n_in; (void)out_size;

    const float* x     = (const float*)d_in[0];
    const int*   ei    = (const int*)d_in[1];
    const float* w0    = (const float*)d_in[2];
    const float* b0    = (const float*)d_in[3];
    const float* w1    = (const float*)d_in[4];
    const float* b1    = (const float*)d_in[5];
    const float* cls_w = (const float*)d_in[6];
    const float* cls_b = (const float*)d_in[7];

    float* logits = (float*)d_out;
    float* feat   = logits + (size_t)N_NODES * NC;   // [N,296]: h1 | h2 | logits

    char* ws = (char*)d_ws;
    int*       cnt  = (int*)(ws + 0);                 // 400 KB
    float*     dis  = (float*)(ws + 400000);          // 400 KB
    int*       adj2 = (int*)(ws + 800000);            // 25.6 MB (100K x 64)
    unsigned*  hbU  = (unsigned*)(ws + 26400000);     // 25.6 MB bf16-pair matrix
    _Float16*  Wt0  = (_Float16*)(ws + 52000000);     // 32 KB
    _Float16*  Wt1  = (_Float16*)(ws + 52032768);     // 32 KB
    _Float16*  Wtc  = (_Float16*)(ws + 52065536);     // 12 KB
    // second hb buffer (fused agg1+gemm2 needs distinct produce/consume buffers)
    const size_t HB2_OFF = 52080000;                  // 16B-aligned
    const size_t NEEDED  = HB2_OFF + (size_t)N_NODES * 256;   // 77.68 MB
    bool big = (ws_size >= NEEDED);
    unsigned* hbU2 = big ? (unsigned*)(ws + HB2_OFF) : hbU;

    // prep_w also zeros cnt (blocks 19..116) -> no separate memset dispatch
    prep_w_kernel<<<117, 256, 0, stream>>>(w0, w1, cls_w, Wt0, Wt1, Wtc, cnt);

    // fused: layer-1 MFMA GEMM (first 1563 blocks) + 8-window bucket fill
    gemm_fill_kernel<<<MF_BLOCKS + FILL_BLOCKS, 256, 0, stream>>>(
        x, Wt0, hbU, ei, cnt, adj2);

    // dis (hb1 stays unscaled; agg1 applies dis[s] at gather time)
    dis_kernel<<<(N_NODES + 255) / 256, 256, 0, stream>>>(cnt, dis);

    if (big) {
        // agg1 fused with gemm2 (h1 -> LDS -> MFMA -> hb2), then agg2 fused with cls
        agg_gemm_kernel<<<FB_BLOCKS, 256, 0, stream>>>(hbU, dis, cnt, adj2, b0, Wt1,
                                                       feat, hbU2);
        agg_cls_kernel<<<FB_BLOCKS, 256, 0, stream>>>(hbU2, dis, cnt, adj2, b1, Wtc,
                                                      cls_b, feat, logits);
    } else {
        // fallback: serial agg1, in-place gemm2, fused agg2+cls
        agg_kernel<<<N_NODES / 4, 256, 0, stream>>>(hbU, dis, cnt, adj2, b0,
                                                    feat + 0, 296);
        gemm_mfma_kernel<<<MF_BLOCKS, 256, 0, stream>>>(feat, 296, Wt1, dis, hbU);
        agg_cls_kernel<<<FB_BLOCKS, 256, 0, stream>>>(hbU, dis, cnt, adj2, b1, Wtc,
                                                      cls_b, feat, logits);
    }
}